// Round 14
// baseline (49.475 us; speedup 1.0000x reference)
//
#include <hip/hip_runtime.h>
#include <math.h>

#define NW 599
#define NRR 598

// async global->LDS DMA, 16 B/lane; LDS dest = wave-uniform base + lane*16
#define GLOAD16(gp, lp)                                                   \
  __builtin_amdgcn_global_load_lds(                                       \
      (const __attribute__((address_space(1))) void*)(gp),                \
      (__attribute__((address_space(3))) void*)(lp), 16, 0, 0)

__device__ inline float wave_allsum(float v) {
#pragma unroll
  for (int o = 32; o > 0; o >>= 1) v += __shfl_xor(v, o);
  return v;
}

// ---------------- kernel A: peaks, persistent + double-buffered ----------------
// Unit = (row, span g): windows 64g..64g+63 <- floats [960g, 960g+976).
// 5120 persistent wave-slots, each owning units slot, slot+5120, ... Each wave
// prefetches unit u+1 into its alternate LDS buffer while computing unit u;
// counted vmcnt(4) drains only the current unit's loads. Barrier-free.
__global__ __launch_bounds__(256) void peaks_kernel(
    const float* __restrict__ x, float* __restrict__ pk, int units,
    int stride) {
  __shared__ float s[4 * 2 * 976];  // 4 waves * 2 bufs * 976 floats (31 KB)
  const int tid = threadIdx.x;
  const int wl = tid >> 6, lane = tid & 63;

  float* bufA = s + wl * 1952;
  float* bufB = bufA + 976;

  int t = blockIdx.x * 4 + wl;  // wave-uniform unit id
  if (t >= units) return;

  // issue loads for first unit into bufA
  {
    const unsigned tu = (unsigned)t;
    const unsigned row = tu / 10u, g = tu % 10u;
    const int nfl = (g < 9u) ? 976 : 360;
    const float* src = x + (size_t)row * 9000 + 960 * g;
#pragma unroll
    for (int j = 0; j < 4; ++j) {
      const int f0 = j * 256 + lane * 4;
      const int f0c = min(f0, nfl - 4);  // clamp: uniform 4 issues/unit
      GLOAD16(src + f0c, bufA + j * 256);
    }
  }

  for (; t < units; t += stride) {
    const int tn = t + stride;
    const bool pre = tn < units;
    if (pre) {  // prefetch next unit into bufB
      const unsigned tu = (unsigned)tn;
      const unsigned row = tu / 10u, g = tu % 10u;
      const int nfl = (g < 9u) ? 976 : 360;
      const float* src = x + (size_t)row * 9000 + 960 * g;
#pragma unroll
      for (int j = 0; j < 4; ++j) {
        const int f0 = j * 256 + lane * 4;
        const int f0c = min(f0, nfl - 4);
        GLOAD16(src + f0c, bufB + j * 256);
      }
      asm volatile("s_waitcnt vmcnt(4)" ::: "memory");  // drain cur unit only
    } else {
      asm volatile("s_waitcnt vmcnt(0)" ::: "memory");
    }

    // compute current unit from bufA
    {
      const unsigned tu = (unsigned)t;
      const unsigned row = tu / 10u, g = tu % 10u;
      const int w = 64 * (int)g + lane;
      if (w < NW) {
        const float* p = bufA + 15 * lane;  // odd stride -> benign bank alias
        float m = p[0];
#pragma unroll
        for (int j = 1; j < 30; ++j) m = fmaxf(m, p[j]);
        float se = 0.f, we = 0.f;
#pragma unroll
        for (int j = 0; j < 30; ++j) {
          float e = __expf((p[j] - m) * 10.0f);  // temp = 0.1
          se += e;
          we += (float)j * e;
        }
        pk[(size_t)row * 600 + w] = we / se + 15.0f * (float)w;
      }
    }

    // swap buffers
    float* tmp = bufA;
    bufA = bufB;
    bufB = tmp;
  }
}

// ---------------- kernel B: features + MLP + LN, barrier-free ----------------
// One wave per row, 8 rows per 512-thread block. No LDS. Lane l owns rr
// indices [10l, 10l+cnt); stats + 12-bin DFT in registers; butterfly sums.
__global__ __launch_bounds__(512, 6) void feat_kernel(
    const float* __restrict__ pk, const float* __restrict__ W1,
    const float* __restrict__ b1, const float* __restrict__ W2,
    const float* __restrict__ b2, const float* __restrict__ gamma,
    const float* __restrict__ beta, float* __restrict__ out, int nrows) {
  const int tid = threadIdx.x;
  const int wid = tid >> 6, lane = tid & 63;
  const int row = blockIdx.x * 8 + wid;
  if (row >= nrows) return;  // wave-uniform exit

  const float* __restrict__ pkr = pk + (size_t)row * 600;
  const int n0 = lane * 10;
  const int cnt = max(0, min(NRR - n0, 10));  // lanes 0-58:10, 59:8, 60-63:0

  const float inv30 = 1.0f / 30.0f;
  float p[11];
#pragma unroll
  for (int j = 0; j < 11; ++j) p[j] = (j <= cnt && cnt > 0) ? pkr[n0 + j] : 0.f;

  float rr[10];
#pragma unroll
  for (int j = 0; j < 10; ++j)
    rr[j] = (j < cnt) ? (p[j + 1] - p[j]) * inv30 : 0.f;

  // stats
  float Srr = 0.f, Srr2 = 0.f, Sd2 = 0.f;
#pragma unroll
  for (int j = 0; j < 10; ++j) {
    Srr += rr[j];
    Srr2 = fmaf(rr[j], rr[j], Srr2);
    if (j < cnt - 1) {
      float d = rr[j + 1] - rr[j];
      Sd2 = fmaf(d, d, Sd2);
    }
  }
  // boundary diff needs neighbor lane's rr[0]
  float nxt0 = __shfl(rr[0], lane + 1);
  if (cnt > 0 && n0 + cnt - 1 <= NRR - 2) {
    float d = nxt0 - rr[cnt - 1];
    Sd2 = fmaf(d, d, Sd2);
  }

  // sparse DFT bins k=2..13 of rfft(rr,1024): base angle + constant-step rotation
  const float c0 = 6.13592315154256491e-3f;  // 2*pi/1024
  float re[12], im[12];
#pragma unroll
  for (int kk = 0; kk < 12; ++kk) {
    const int k = kk + 2;
    float cb, sb, cs, ss;
    __sincosf((float)((k * n0) & 1023) * c0, &sb, &cb);
    __sincosf((float)k * c0, &ss, &cs);
    float r = 0.f, i2 = 0.f;
#pragma unroll
    for (int j = 0; j < 10; ++j) {
      if (j < cnt) {
        r = fmaf(rr[j], cb, r);
        i2 = fmaf(-rr[j], sb, i2);
      }
      float cb2 = cb * cs - sb * ss;  // rotate by step
      sb = fmaf(sb, cs, cb * ss);
      cb = cb2;
    }
    re[kk] = r;
    im[kk] = i2;
  }

  // wave reductions (butterfly -> all lanes hold totals)
  Srr = wave_allsum(Srr);
  Srr2 = wave_allsum(Srr2);
  Sd2 = wave_allsum(Sd2);
  float lf = 0.f, hf = 0.f;
#pragma unroll
  for (int kk = 0; kk < 12; ++kk) {
    float r = wave_allsum(re[kk]);
    float i2 = wave_allsum(im[kk]);
    float pw = fmaf(r, r, i2 * i2);
    if (kk < 4) lf += pw; else hf += pw;
  }

  const float mean = Srr * (1.0f / (float)NRR);
  const float var =
      (Srr2 - (float)NRR * mean * mean) * (1.0f / (float)(NRR - 1));
  const float sdnn = sqrtf(fmaxf(var, 0.f));
  const float rmssd = sqrtf(Sd2 * (1.0f / (float)(NRR - 1)) + 1e-6f);

  // MLP layer 1: h1[lane]
  float h1 = b1[lane];
  h1 = fmaf(mean, W1[lane], h1);
  h1 = fmaf(rmssd, W1[64 + lane], h1);
  h1 = fmaf(sdnn, W1[128 + lane], h1);
  h1 = fmaf(lf, W1[192 + lane], h1);
  h1 = fmaf(hf, W1[256 + lane], h1);
  h1 = fmaxf(h1, 0.f);

  // MLP layer 2: outputs lane and lane+64
  float a0 = b2[lane], a1 = b2[64 + lane];
#pragma unroll 8
  for (int i = 0; i < 64; ++i) {
    float hv = __shfl(h1, i);
    a0 = fmaf(hv, W2[i * 128 + lane], a0);
    a1 = fmaf(hv, W2[i * 128 + 64 + lane], a1);
  }

  // LayerNorm over 128
  const float mu = wave_allsum(a0 + a1) * (1.0f / 128.0f);
  const float vv =
      wave_allsum((a0 - mu) * (a0 - mu) + (a1 - mu) * (a1 - mu)) *
      (1.0f / 128.0f);
  const float inv = rsqrtf(vv + 1e-5f);
  out[(size_t)row * 128 + lane] = (a0 - mu) * inv * gamma[lane] + beta[lane];
  out[(size_t)row * 128 + 64 + lane] =
      (a1 - mu) * inv * gamma[64 + lane] + beta[64 + lane];
}

extern "C" void kernel_launch(void* const* d_in, const int* in_sizes, int n_in,
                              void* d_out, int out_size, void* d_ws,
                              size_t ws_size, hipStream_t stream) {
  const float* x = (const float*)d_in[0];
  const float* W1 = (const float*)d_in[1];
  const float* b1 = (const float*)d_in[2];
  const float* W2 = (const float*)d_in[3];
  const float* b2 = (const float*)d_in[4];
  const float* gamma = (const float*)d_in[5];
  const float* beta = (const float*)d_in[6];
  float* out = (float*)d_out;

  const int B = in_sizes[0] / 9000;
  float* pk = (float*)d_ws;  // B*600 floats = 9.8 MB << ws_size

  const int units = B * 10;
  int grid = 1280;  // 5 blocks/CU * 256 CU (LDS-limited residency)
  if (grid > (units + 3) / 4) grid = (units + 3) / 4;
  const int stride = grid * 4;

  peaks_kernel<<<grid, 256, 0, stream>>>(x, pk, units, stride);
  feat_kernel<<<(B + 7) / 8, 512, 0, stream>>>(pk, W1, b1, W2, b2, gamma, beta,
                                               out, B);
}